// Round 11
// baseline (11685.561 us; speedup 1.0000x reference)
//
#include <hip/hip_runtime.h>
#include <hip/hip_bf16.h>

#define T_STEPS 800
#define BATCH   32
#define FEAT    161
#define UNITS   1024
#define CLIPV   20.0f
#define TEST_BUDGET 65536

typedef __attribute__((ext_vector_type(8))) short short8;
typedef __attribute__((ext_vector_type(4))) float f32x4;
typedef __attribute__((ext_vector_type(4))) unsigned int u32x4;
typedef unsigned short u16;
typedef unsigned int   u32;
typedef unsigned long long u64;

__device__ __forceinline__ float bf16_f(u16 u) {
    return __uint_as_float(((u32)u) << 16);
}
__device__ __forceinline__ u16 bf16_rn(float x) {
    __hip_bfloat16 b = __float2bfloat16(x);
    return *(u16*)&b;
}
__device__ __forceinline__ u64 ld_agent_u64(const u64* p) {
    return __hip_atomic_load(p, __ATOMIC_RELAXED, __HIP_MEMORY_SCOPE_AGENT);
}
__device__ __forceinline__ u32 ld_agent_u32(const u32* p) {
    return __hip_atomic_load(p, __ATOMIC_RELAXED, __HIP_MEMORY_SCOPE_AGENT);
}
__device__ __forceinline__ float ld_agent_f(const float* p) {
    return __hip_atomic_load(p, __ATOMIC_RELAXED, __HIP_MEMORY_SCOPE_AGENT);
}
__device__ __forceinline__ void st_agent_u32(u32* p, u32 v) {
    __hip_atomic_store(p, v, __ATOMIC_RELAXED, __HIP_MEMORY_SCOPE_AGENT);
}
__device__ __forceinline__ void st_agent_f(float* p, float v) {
    __hip_atomic_store(p, v, __ATOMIC_RELAXED, __HIP_MEMORY_SCOPE_AGENT);
}
__device__ __forceinline__ short8 ld_agent_b16x8(const u16* p) {
    union { u64 q[2]; short8 v; } u;
    u.q[0] = ld_agent_u64((const u64*)p);
    u.q[1] = ld_agent_u64((const u64*)p + 1);
    return u.v;
}
// --- XCD-local primitives: plain store (dirty in home L2, write-through L1),
//     sc0 load (L1-bypass, served by the XCD's L2) ---
__device__ __forceinline__ u32 ld_sc0_u32(const u32* p) {
    u32 v;
    asm volatile("global_load_dword %0, %1, off sc0\n\ts_waitcnt vmcnt(0)"
                 : "=&v"(v) : "v"(p) : "memory");
    return v;
}
__device__ __forceinline__ u32x4 ld_sc0_u32x4(const u32* p) {
    u32x4 v;
    asm volatile("global_load_dwordx4 %0, %1, off sc0\n\ts_waitcnt vmcnt(0)"
                 : "=&v"(v) : "v"(p) : "memory");
    return v;
}
__device__ __forceinline__ float ld_sc0_f(const float* p) {
    float v;
    asm volatile("global_load_dword %0, %1, off sc0\n\ts_waitcnt vmcnt(0)"
                 : "=&v"(v) : "v"(p) : "memory");
    return v;
}
__device__ __forceinline__ void st_plain_u32(u32* p, u32 v) {
    asm volatile("global_store_dword %0, %1, off" :: "v"(p), "v"(v) : "memory");
}
__device__ __forceinline__ void st_plain_f(float* p, float v) {
    asm volatile("global_store_dword %0, %1, off" :: "v"(p), "v"(v) : "memory");
}
__device__ __forceinline__ void wait_vm0() {
    asm volatile("s_waitcnt vmcnt(0)" ::: "memory");
}
struct Q8 { f32x4 a, b, c, d, e, f, g, h; };
// 8 x 16B: one row's 4 k-subslices (float offsets 0/4, 32/36, 64/68, 96/100)
__device__ __forceinline__ Q8 ld_sc0_q8(const float* ab) {
    Q8 r;
    asm volatile(
        "global_load_dwordx4 %0, %8, off sc0\n\t"
        "global_load_dwordx4 %1, %8, off offset:16 sc0\n\t"
        "global_load_dwordx4 %2, %8, off offset:128 sc0\n\t"
        "global_load_dwordx4 %3, %8, off offset:144 sc0\n\t"
        "global_load_dwordx4 %4, %8, off offset:256 sc0\n\t"
        "global_load_dwordx4 %5, %8, off offset:272 sc0\n\t"
        "global_load_dwordx4 %6, %8, off offset:384 sc0\n\t"
        "global_load_dwordx4 %7, %8, off offset:400 sc0\n\t"
        "s_waitcnt vmcnt(0)"
        : "=&v"(r.a), "=&v"(r.b), "=&v"(r.c), "=&v"(r.d),
          "=&v"(r.e), "=&v"(r.f), "=&v"(r.g), "=&v"(r.h)
        : "v"(ab) : "memory");
    return r;
}

// ctrl layout (u32 words):
#define C_ARRIVE   0
#define C_FINDONE  16
#define C_XCD      32     // 256 words
#define C_TW       320    // + g*64 (32 words used per group)
#define C_RES      576    // + g*64 (32 words used per group)
#define CTRL_WORDS 1024

// ---------------------------------------------------------------------------
__global__ __launch_bounds__(256) void init_ws(float* hbuf, u32* flags, u32* ctrl) {
    int gid = blockIdx.x * 256 + threadIdx.x;          // 16384 threads
    for (int i = gid; i < 2 * 64 * UNITS; i += 64 * 256) hbuf[i] = 0.f;
    if (gid < 128) flags[gid] = 0u;
    if (gid < CTRL_WORDS) ctrl[gid] = 0u;
}

// ---------------------------------------------------------------------------
// Ut splits: U[k][u] fp32 -> Ut1/2/3[u][k] bf16 (hi/mid/lo, 24-bit total)
__global__ __launch_bounds__(256) void u_split_t(const float* __restrict__ U,
                                                 u16* __restrict__ Ut1,
                                                 u16* __restrict__ Ut2,
                                                 u16* __restrict__ Ut3) {
    __shared__ float tile[32][33];
    int bx = blockIdx.x, by = blockIdx.y;
    int lx = threadIdx.x & 31;
    int ly4 = (threadIdx.x >> 5) * 4;
    #pragma unroll
    for (int j = 0; j < 4; ++j)
        tile[ly4 + j][lx] = U[(size_t)(by * 32 + ly4 + j) * UNITS + bx * 32 + lx];
    __syncthreads();
    #pragma unroll
    for (int j = 0; j < 4; ++j) {
        float x = tile[lx][ly4 + j];
        size_t o = (size_t)(bx * 32 + ly4 + j) * UNITS + by * 32 + lx;
        u16 s1 = bf16_rn(x);  float r1 = x - bf16_f(s1);
        u16 s2 = bf16_rn(r1); float r2 = r1 - bf16_f(s2);
        u16 s3 = bf16_rn(r2);
        Ut1[o] = s1; Ut2[o] = s2; Ut3[o] = s3;
    }
}

// ---------------------------------------------------------------------------
__global__ __launch_bounds__(256) void xw_gemm(const float* __restrict__ inp,
                                               const float* __restrict__ W,
                                               const float* __restrict__ bias,
                                               float* __restrict__ xW) {
    __shared__ float xs[8 * FEAT];
    int t = blockIdx.x;
    int b0 = blockIdx.y * 8;
    int tid = threadIdx.x;

    for (int i = tid; i < 8 * FEAT; i += 256) {
        int j = i / FEAT;
        int f = i - j * FEAT;
        xs[i] = inp[((size_t)(b0 + j) * T_STEPS + t) * FEAT + f];
    }
    __syncthreads();

    float bv[4];
    #pragma unroll
    for (int c = 0; c < 4; ++c) bv[c] = bias[tid + c * 256];

    float acc[8][4];
    #pragma unroll
    for (int j = 0; j < 8; ++j)
        #pragma unroll
        for (int c = 0; c < 4; ++c) acc[j][c] = bv[c];

    for (int f = 0; f < FEAT; ++f) {
        float w0 = W[(size_t)f * UNITS + tid];
        float w1 = W[(size_t)f * UNITS + tid + 256];
        float w2 = W[(size_t)f * UNITS + tid + 512];
        float w3 = W[(size_t)f * UNITS + tid + 768];
        #pragma unroll
        for (int j = 0; j < 8; ++j) {
            float xv = xs[j * FEAT + f];
            acc[j][0] += xv * w0;
            acc[j][1] += xv * w1;
            acc[j][2] += xv * w2;
            acc[j][3] += xv * w3;
        }
    }

    #pragma unroll
    for (int j = 0; j < 8; ++j)
        #pragma unroll
        for (int c = 0; c < 4; ++c)
            xW[((size_t)t * BATCH + b0 + j) * UNITS + tid + c * 256] = acc[j][c];
}

// ---------------------------------------------------------------------------
// R5 protocol + measured-XCD election. 256 blocks x 512 threads (cooperative).
// Election: every block publishes its HW_REG_XCC_ID; after a counted barrier
// every block computes the SAME deterministic assignment from the published
// array: 4 groups x 32 slots, group g = first 32 blocks (by id) of the g-th
// most-populated XCD (ties by XCD id). Groups whose XCD has <32 blocks are
// filled from the leftover pool and run AGENT mode (byte-identical R5 path).
// Preflight (local groups): each member plain-stores a self-validating magic
// word; all members sc0-poll all 32 words with a bounded budget; consensus
// through agent-scope result words. Any timeout -> whole group AGENT.
// LOCAL exchange: h + flags via plain stores (dirty in the home XCD L2,
// L1 write-through) + sc0 loads (L1-bypass, L2-served): ~250cy hops vs ~900.
// Protocol per step (identical ordering in both modes, R5-proven):
//   poll 4 source flags (16B) -> load A slices -> split -> MFMA -> LDS reduce
//   (kq0) -> store h tile -> barrier (vmcnt drain) -> publish flag t+1.
// WAR-safe: all 8 waves jointly observe all 32 member flags >= t before the
// block's step-t store (store follows the all-wave barrier), so nobody
// overwrites a buffer that any member is still reading.
// Final output crosses groups -> every block republishes its final tile to
// finbuf at agent scope (local groups' h is dirty-L2 only).
__global__ __launch_bounds__(512) void rnn_scan(
        const float* __restrict__ xW,
        const u16* __restrict__ Ut1, const u16* __restrict__ Ut2,
        const u16* __restrict__ Ut3,
        float* __restrict__ hbuf, float* __restrict__ finbuf,
        u32* __restrict__ flags, u32* __restrict__ ctrl,
        float* __restrict__ out) {
    __shared__ f32x4 red[14][64];          // 14 KB (R5 layout, 0 conflicts)
    __shared__ unsigned char sxcd[256];
    __shared__ int s_g, s_slot, s_mode;    // mode: 0 = local, 1 = agent

    const int tid = threadIdx.x;
    const int bk  = blockIdx.x;

    // ---------------- election (tid 0; deterministic on all blocks) --------
    if (tid == 0) {
        int xcd;
        asm volatile("s_getreg_b32 %0, hwreg(HW_REG_XCC_ID)" : "=s"(xcd));
        xcd &= 7;
        st_agent_u32(ctrl + C_XCD + bk, (u32)xcd);
        wait_vm0();
        __hip_atomic_fetch_add(ctrl + C_ARRIVE, 1u, __ATOMIC_RELAXED,
                               __HIP_MEMORY_SCOPE_AGENT);
        while (ld_agent_u32(ctrl + C_ARRIVE) < 256u) __builtin_amdgcn_s_sleep(4);

        int cnt[8] = {0,0,0,0,0,0,0,0};
        for (int j = 0; j < 256; ++j) {
            u32 x = ld_agent_u32(ctrl + C_XCD + j) & 7u;
            sxcd[j] = (unsigned char)x;
            cnt[x]++;
        }
        int sel[4], selLoc[4], used[8] = {0,0,0,0,0,0,0,0};
        for (int g2 = 0; g2 < 4; ++g2) {
            int best = -1;
            for (int X = 0; X < 8; ++X)
                if (!used[X] && (best < 0 || cnt[X] > cnt[best])) best = X;
            used[best] = 1; sel[g2] = best; selLoc[g2] = (cnt[best] >= 32);
        }
        int running[8] = {0,0,0,0,0,0,0,0};
        int poolBefore = 0, myG = -1, mySlot = 0, myMode = 1, myPool = -1;
        for (int j = 0; j < 256; ++j) {
            int x = sxcd[j];
            int r = running[x]++;
            int cg = -1;
            for (int g2 = 0; g2 < 4; ++g2)
                if (selLoc[g2] && sel[g2] == x && r < 32) cg = g2;
            if (j == bk) {
                if (cg >= 0) { myG = cg; mySlot = r; myMode = 0; }
                else         { myPool = poolBefore; }
            }
            if (cg < 0) poolBefore++;
        }
        if (myG < 0 && myPool >= 0) {      // fill agent groups from the pool
            int agList[4], na = 0;
            for (int g2 = 0; g2 < 4; ++g2) if (!selLoc[g2]) agList[na++] = g2;
            if (myPool < na * 32) {
                myG = agList[myPool / 32]; mySlot = myPool % 32; myMode = 1;
            }
        }
        s_g = myG; s_slot = mySlot; s_mode = myMode;
    }
    __syncthreads();
    const int g = s_g, slot = s_slot;
    if (g < 0) return;                      // spare block

    // ---------------- preflight handshake for local groups -----------------
    if (s_mode == 0) {
        if (tid == 0) {
            u32* tw  = ctrl + C_TW  + g * 64;
            u32* res = ctrl + C_RES + g * 64;
            const u32 MAG = 0xC0FFEE00u;
            st_plain_u32(tw + slot, MAG | (u32)slot);
            wait_vm0();
            int budget = TEST_BUDGET, pass = 1;
            for (int s = 0; s < 32 && pass; ++s)
                while (ld_sc0_u32(tw + s) != (MAG | (u32)s))
                    if (--budget <= 0) { pass = 0; break; }
            st_agent_u32(res + slot, pass ? 1u : 2u);
            wait_vm0();
            u32 allok = 1;
            for (int s = 0; s < 32; ++s) {
                u32 v;
                do { v = ld_agent_u32(res + s); } while (v == 0u);
                allok &= (v == 1u);
            }
            s_mode = allok ? 0 : 1;
        }
        __syncthreads();
    }
    const int mode = s_mode;                // 0 local, 1 agent — fixed for run

    const int lane = tid & 63;
    const int kq   = tid >> 6;
    const int quad = lane >> 4;
    const int n16  = lane & 15;
    const int R0   = g * 16;
    const int u0   = slot * 32;
    const int dir  = g >> 1;

    u32* myflag = flags + g * 32 + slot;
    u32* fpoll  = flags + g * 32 + kq * 4;  // 16B aligned, 4 source writers

    // --- B fragments: U splits (agent loads -> pinned, 96 VGPRs) ---
    short8 bfr[4][2][3];
    #pragma unroll
    for (int ks = 0; ks < 4; ++ks) {
        const int koff = kq * 128 + ks * 32 + quad * 8;
        #pragma unroll
        for (int nq = 0; nq < 2; ++nq) {
            const size_t ub = (size_t)(u0 + nq * 16 + n16) * UNITS + koff;
            bfr[ks][nq][0] = ld_agent_b16x8(Ut1 + ub);
            bfr[ks][nq][1] = ld_agent_b16x8(Ut2 + ub);
            bfr[ks][nq][2] = ld_agent_b16x8(Ut3 + ub);
        }
    }

    const size_t HS = (size_t)64 * UNITS;

    for (int t = 0; t < T_STEPS; ++t) {
        const size_t sb = (size_t)(t & 1) * HS;
        const size_t db = sb ^ HS;
        const u32 tgt = (u32)t;

        // xW prefetch (combining wave only)
        float xp[2][4];
        if (kq == 0) {
            const int xt = dir ? (T_STEPS - 1 - t) : t;
            #pragma unroll
            for (int nq = 0; nq < 2; ++nq)
                #pragma unroll
                for (int j = 0; j < 4; ++j) {
                    const int b = (R0 + quad * 4 + j) & 31;
                    xp[nq][j] = xW[(size_t)xt * (BATCH * UNITS) +
                                   (size_t)b * UNITS + u0 + nq * 16 + n16];
                }
        }

        // ---- poll the 4 source-writer flags (R5 semantics) ----
        if (mode == 0) {
            for (;;) {
                u32x4 f = ld_sc0_u32x4(fpoll);
                if (f.x >= tgt && f.y >= tgt && f.z >= tgt && f.w >= tgt) break;
            }
        } else {
            const u64* sf = (const u64*)fpoll;
            for (;;) {
                u64 qa = ld_agent_u64(sf), qb = ld_agent_u64(sf + 1);
                if ((u32)qa >= tgt && (u32)(qa >> 32) >= tgt &&
                    (u32)qb >= tgt && (u32)(qb >> 32) >= tgt) break;
            }
        }

        // ---- load A (this wave's 128-k slice of 16 rows) ----
        union HU { f32x4 v4[2]; u64 q[2]; float fl[8]; u32 u[8]; } hu[4];
        const float* ab = hbuf + sb + (size_t)(R0 + n16) * UNITS +
                          kq * 128 + quad * 8;
        if (mode == 0) {
            Q8 q8 = ld_sc0_q8(ab);
            hu[0].v4[0] = q8.a; hu[0].v4[1] = q8.b;
            hu[1].v4[0] = q8.c; hu[1].v4[1] = q8.d;
            hu[2].v4[0] = q8.e; hu[2].v4[1] = q8.f;
            hu[3].v4[0] = q8.g; hu[3].v4[1] = q8.h;
        } else {
            #pragma unroll
            for (int ks = 0; ks < 4; ++ks) {
                const u64* sp = (const u64*)(ab + ks * 32);
                hu[ks].q[0] = ld_agent_u64(sp);
                hu[ks].q[1] = ld_agent_u64(sp + 1);
                ((u64*)&hu[ks].v4[1])[0] = ld_agent_u64(sp + 2);
                ((u64*)&hu[ks].v4[1])[1] = ld_agent_u64(sp + 3);
            }
        }

        // ---- split to 3 bf16 planes + MFMA (fp32-equivalent) ----
        f32x4 acc[2][2] = {{{0.f,0.f,0.f,0.f},{0.f,0.f,0.f,0.f}},
                           {{0.f,0.f,0.f,0.f},{0.f,0.f,0.f,0.f}}};
        #pragma unroll
        for (int ks = 0; ks < 4; ++ks) {
            short8 a1, a2, a3;
            #pragma unroll
            for (int j = 0; j < 8; ++j) {
                u32 xb = hu[ks].u[j];
                float x = __uint_as_float(xb);
                u16 s1 = (u16)(xb >> 16);
                float r1 = x - bf16_f(s1);
                u16 s2 = (u16)(__float_as_uint(r1) >> 16);
                float r2 = r1 - bf16_f(s2);
                u16 s3 = (u16)(__float_as_uint(r2) >> 16);
                a1[j] = (short)s1; a2[j] = (short)s2; a3[j] = (short)s3;
            }
            #pragma unroll
            for (int nq = 0; nq < 2; ++nq) {
                acc[nq][0] = __builtin_amdgcn_mfma_f32_16x16x32_bf16(a1, bfr[ks][nq][0], acc[nq][0], 0, 0, 0);
                acc[nq][1] = __builtin_amdgcn_mfma_f32_16x16x32_bf16(a2, bfr[ks][nq][0], acc[nq][1], 0, 0, 0);
                acc[nq][0] = __builtin_amdgcn_mfma_f32_16x16x32_bf16(a1, bfr[ks][nq][1], acc[nq][0], 0, 0, 0);
                acc[nq][1] = __builtin_amdgcn_mfma_f32_16x16x32_bf16(a2, bfr[ks][nq][1], acc[nq][1], 0, 0, 0);
                acc[nq][0] = __builtin_amdgcn_mfma_f32_16x16x32_bf16(a1, bfr[ks][nq][2], acc[nq][0], 0, 0, 0);
                acc[nq][1] = __builtin_amdgcn_mfma_f32_16x16x32_bf16(a3, bfr[ks][nq][0], acc[nq][1], 0, 0, 0);
            }
        }
        f32x4 c0 = acc[0][0] + acc[0][1];
        f32x4 c1 = acc[1][0] + acc[1][1];

        // ---- cross-wave k-reduction (R5 layout, 0 bank conflicts) ----
        if (kq) {
            red[(kq - 1) * 2 + 0][lane] = c0;
            red[(kq - 1) * 2 + 1][lane] = c1;
        }
        __syncthreads();
        if (kq == 0) {
            #pragma unroll
            for (int w = 0; w < 7; ++w) {
                c0 += red[w * 2 + 0][lane];
                c1 += red[w * 2 + 1][lane];
            }
            float* hdst = hbuf + db;
            #pragma unroll
            for (int nq = 0; nq < 2; ++nq)
                #pragma unroll
                for (int j = 0; j < 4; ++j) {
                    float a = (nq ? c1[j] : c0[j]) + xp[nq][j];
                    a = fminf(fmaxf(a, 0.f), CLIPV);
                    float* dp = hdst + (size_t)(R0 + quad * 4 + j) * UNITS +
                                u0 + nq * 16 + n16;
                    if (mode == 0) st_plain_f(dp, a);
                    else           st_agent_f(dp, a);
                }
        }
        __syncthreads();     // red[] reuse + (agent) compiler vmcnt drain
        if (tid == 0) {
            if (mode == 0) { wait_vm0(); st_plain_u32(myflag, (u32)(t + 1)); }
            else           { st_agent_u32(myflag, (u32)(t + 1)); }
        }
    }

    // ---- final: republish own tile (buffer 0) agent-visibly, then combine --
    {
        const int r = tid >> 5, c = tid & 31;
        const size_t off = (size_t)(R0 + r) * UNITS + u0 + c;
        float v = (mode == 0) ? ld_sc0_f(hbuf + off) : ld_agent_f(hbuf + off);
        st_agent_f(finbuf + off, v);
    }
    __syncthreads();         // drains every wave's agent stores
    if (tid == 0)
        __hip_atomic_fetch_add(ctrl + C_FINDONE, 1u, __ATOMIC_RELAXED,
                               __HIP_MEMORY_SCOPE_AGENT);

    if (g < 2) {             // forward groups write the output
        if (tid == 0)
            while (ld_agent_u32(ctrl + C_FINDONE) < 128u)
                __builtin_amdgcn_s_sleep(1);
        __syncthreads();
        const int r = tid >> 5, c = tid & 31;
        const int b = R0 + r;
        float hf = ld_agent_f(finbuf + (size_t)b * UNITS + u0 + c);
        float hb = ld_agent_f(finbuf + (size_t)(b + 32) * UNITS + u0 + c);
        out[(size_t)b * UNITS + u0 + c] = hf + hb;
    }
}

// ---------------------------------------------------------------------------
extern "C" void kernel_launch(void* const* d_in, const int* in_sizes, int n_in,
                              void* d_out, int out_size, void* d_ws, size_t ws_size,
                              hipStream_t stream) {
    const float* inp  = (const float*)d_in[0];   // [32][800][161]
    const float* W    = (const float*)d_in[1];   // [161][1024]
    const float* U    = (const float*)d_in[2];   // [1024][1024]
    const float* bias = (const float*)d_in[3];   // [1024]
    float* out = (float*)d_out;                  // [32][1024]

    u16*   Ut1 = (u16*)d_ws;                              // 3 x 2 MB bf16 planes
    u16*   Ut2 = Ut1 + (size_t)UNITS * UNITS;
    u16*   Ut3 = Ut2 + (size_t)UNITS * UNITS;
    float* xW  = (float*)(Ut3 + (size_t)UNITS * UNITS);   // 104.9 MB
    float* hbuf   = xW + (size_t)T_STEPS * BATCH * UNITS; // 2 x 256 KB
    float* finbuf = hbuf + (size_t)2 * 64 * UNITS;        // 256 KB
    u32*   flags  = (u32*)(finbuf + (size_t)64 * UNITS);  // 128 words
    u32*   ctrl   = flags + 128;                          // 1024 words

    init_ws<<<64, 256, 0, stream>>>(hbuf, flags, ctrl);
    u_split_t<<<dim3(32, 32), 256, 0, stream>>>(U, Ut1, Ut2, Ut3);
    xw_gemm<<<dim3(800, 4), 256, 0, stream>>>(inp, W, bias, xW);

    void* args[] = {(void*)&xW, (void*)&Ut1, (void*)&Ut2, (void*)&Ut3,
                    (void*)&hbuf, (void*)&finbuf, (void*)&flags, (void*)&ctrl,
                    (void*)&out};
    hipLaunchCooperativeKernel((const void*)rnn_scan, dim3(256), dim3(512),
                               args, 0, stream);
}